// Round 5
// baseline (737.807 us; speedup 1.0000x reference)
//
#include <hip/hip_runtime.h>
#include <hip/hip_bf16.h>
#include <math.h>

#define NF 500
#define HID 64
#define NCLS 40
#define NPART 8
#define SCHUNK 4096
#define KSTEPS 16   // ceil(500/32)

typedef __attribute__((ext_vector_type(8))) short short8v;
typedef __attribute__((ext_vector_type(4))) float f32x4v;

__device__ inline short f2bf(float f) {
  unsigned u = __float_as_uint(f);
  unsigned r = u + 0x7fff + ((u >> 16) & 1);   // RNE
  return (short)(r >> 16);
}
__device__ inline float bf2f(unsigned short u) {
  return __uint_as_float(((unsigned)u) << 16);
}

// cvec layout: [0,64) c1 slope for t>=0 ; [64,128) c1 slope for t<0 ;
//              [128,168) c2 slope for t>=0 ; [168,208) c2 slope for t<0

__global__ void prep_kernel(const float* __restrict__ m1a, const float* __restrict__ m1bw,
                            const float* __restrict__ m2a, const float* __restrict__ m2bw,
                            float* __restrict__ c) {
  int j = threadIdx.x;
  if (j < HID) {
    float sp = 0.f, sn = 0.f;
    for (int k = 0; k < HID; ++k) {
      float a = m1a[k];
      float ap = a > 0.f ? a : 0.2f * a;
      float an = a > 0.f ? 0.2f * a : a;
      float w = m1bw[k * HID + j];
      sp = fmaf(ap, w, sp);
      sn = fmaf(an, w, sn);
    }
    c[j] = sp;
    c[HID + j] = sn;
  }
  if (j < NCLS) {
    float sp = 0.f, sn = 0.f;
    for (int k = 0; k < NCLS; ++k) {
      float a = m2a[k];
      float ap = a > 0.f ? a : 0.2f * a;
      float an = a > 0.f ? 0.2f * a : a;
      float w = m2bw[k * NCLS + j];
      sp = fmaf(ap, w, sp);
      sn = fmaf(an, w, sn);
    }
    c[128 + j] = sp;
    c[168 + j] = sn;
  }
}

// w1 -> bf16 in B-fragment-linear layout
__global__ void wprep_kernel(const float* __restrict__ w1, short* __restrict__ wf) {
  int idx = blockIdx.x * 256 + threadIdx.x;   // 0..4095
  if (idx >= KSTEPS * 4 * 64) return;
  int l = idx & 63;
  int f = (idx >> 6) & 3;
  int s = idx >> 8;
  int ch = f * 16 + (l & 15);
  int kb = s * 32 + (l >> 4) * 8;
  short8v v;
#pragma unroll
  for (int j = 0; j < 8; ++j) {
    int k = kb + j;
    v[j] = (k < NF) ? f2bf(w1[(size_t)k * HID + ch]) : (short)0;
  }
  ((short8v*)wf)[idx] = v;
}

__global__ void hist_kernel(const int* __restrict__ ei, int E,
                            int* __restrict__ deg_src, int* __restrict__ deg_dst) {
  int i = blockIdx.x * blockDim.x + threadIdx.x;
  if (i < E) {
    int s = __builtin_nontemporal_load(ei + i);
    int d = __builtin_nontemporal_load(ei + E + i);
    atomicAdd(&deg_src[s], 1);
    atomicAdd(&deg_dst[d], 1);
  }
}

// ---- multi-block exclusive scan of two degree arrays ----
__global__ __launch_bounds__(256) void scanA_kernel(const int* __restrict__ a,
    const int* __restrict__ b, int n, int nc, int* __restrict__ part) {
  const int bi = blockIdx.x;
  const int* arr = (bi < nc) ? a : b;
  const int ci = (bi < nc) ? bi : bi - nc;
  const int base = ci * SCHUNK;
  int s = 0;
  for (int u = threadIdx.x; u < SCHUNK; u += 256) {
    int i = base + u;
    if (i < n) s += arr[i];
  }
  __shared__ int ws[4];
#pragma unroll
  for (int off = 32; off > 0; off >>= 1) s += __shfl_down(s, off);
  if ((threadIdx.x & 63) == 0) ws[threadIdx.x >> 6] = s;
  __syncthreads();
  if (threadIdx.x == 0) part[bi] = ws[0] + ws[1] + ws[2] + ws[3];
}

__global__ void scanB_kernel(int* __restrict__ part, int nc,
                             int* __restrict__ a, int* __restrict__ b, int n) {
  int lane = threadIdx.x;  // 64 threads
  for (int seg = 0; seg < 2; ++seg) {
    int v = (lane < nc) ? part[seg * nc + lane] : 0;
    int x = v;
#pragma unroll
    for (int off = 1; off < 64; off <<= 1) {
      int y = __shfl_up(x, off);
      if (lane >= off) x += y;
    }
    if (lane < nc) part[seg * nc + lane] = x - v;
    int tot = __shfl(x, 63);
    if (lane == 0) { if (seg == 0) a[n] = tot; else b[n] = tot; }
  }
}

__global__ __launch_bounds__(256) void scanC_kernel(int* __restrict__ a, int* __restrict__ cura,
    int* __restrict__ b, int* __restrict__ curb, int n, int nc, const int* __restrict__ part) {
  const int bi = blockIdx.x;
  int* arr; int* cur; int ci;
  if (bi < nc) { arr = a; cur = cura; ci = bi; }
  else         { arr = b; cur = curb; ci = bi - nc; }
  const int chunkoff = part[bi];
  const int base = ci * SCHUNK + threadIdx.x * 16;
  int v[16];
#pragma unroll
  for (int u = 0; u < 16; ++u) {
    int i = base + u;
    v[u] = (i < n) ? arr[i] : 0;
  }
  int tsum = 0;
#pragma unroll
  for (int u = 0; u < 16; ++u) tsum += v[u];
  const int lane = threadIdx.x & 63, wv = threadIdx.x >> 6;
  int x = tsum;
#pragma unroll
  for (int off = 1; off < 64; off <<= 1) {
    int y = __shfl_up(x, off);
    if (lane >= off) x += y;
  }
  __shared__ int ws[4];
  if (lane == 63) ws[wv] = x;
  __syncthreads();
  int woff = 0;
  for (int k = 0; k < wv; ++k) woff += ws[k];
  int toff = chunkoff + woff + x - tsum;
#pragma unroll
  for (int u = 0; u < 16; ++u) {
    int i = base + u;
    if (i < n) { arr[i] = toff; cur[i] = toff; }
    toff += v[u];
  }
}

// ---- partition-localized CSR scatter, nt streaming reads ----
// pair[] entries packed as (long long): low 32 = src index, high 32 = t bits
__global__ __launch_bounds__(256) void scatter_kernel(const int* __restrict__ ei,
    const float* __restrict__ wmul, int E,
    int* __restrict__ cur_src, int* __restrict__ cur_dst,
    float* __restrict__ t_src, long long* __restrict__ pair, int N, int rng) {
  const int part = blockIdx.x & (NPART - 1);
  const int e = (blockIdx.x >> 3) * 256 + threadIdx.x;
  if (e >= E) return;
  const int lo = part * rng;
  const int hi = min(N, lo + rng);
  int s = __builtin_nontemporal_load(ei + e);
  int d = __builtin_nontemporal_load(ei + E + e);
  bool ss = (s >= lo) && (s < hi);
  bool dd = (d >= lo) && (d < hi);
  if (!(ss || dd)) return;
  float t = __builtin_nontemporal_load(wmul + e);
  if (ss) { int ps = atomicAdd(&cur_src[s], 1); t_src[ps] = t; }
  if (dd) {
    int pd = atomicAdd(&cur_dst[d], 1);
    long long pk = (long long)((unsigned long long)(unsigned)__float_as_uint(t) << 32) |
                   (unsigned long long)(unsigned)s;
    pair[pd] = pk;
  }
}

// h1 = x @ w1 + b1 via bf16 MFMA
__global__ __launch_bounds__(256, 4) void gemm1_mfma(const float* __restrict__ x,
    const short* __restrict__ wf, const float* __restrict__ b1,
    float* __restrict__ h1, int N) {
  const int tid = threadIdx.x;
  const int wv = tid >> 6, l = tid & 63;
  const int lr = l & 15, lk = l >> 4;
  const int n0 = blockIdx.x * 128 + wv * 32;
  int r0 = n0 + lr, r1 = r0 + 16;
  const float* p0 = x + (size_t)min(r0, N - 1) * NF + lk * 8;
  const float* p1 = x + (size_t)min(r1, N - 1) * NF + lk * 8;
  const short8v* wfv = (const short8v*)wf;

  f32x4v acc[2][4];
#pragma unroll
  for (int mi = 0; mi < 2; ++mi)
#pragma unroll
    for (int f = 0; f < 4; ++f) acc[mi][f] = (f32x4v){0.f, 0.f, 0.f, 0.f};

  const float4 z4 = make_float4(0.f, 0.f, 0.f, 0.f);
#pragma unroll
  for (int s = 0; s < KSTEPS; ++s) {
    float4 a0l, a0h, a1l, a1h;
    if (s < KSTEPS - 1) {
      a0l = *(const float4*)(p0 + s * 32);
      a0h = *(const float4*)(p0 + s * 32 + 4);
      a1l = *(const float4*)(p1 + s * 32);
      a1h = *(const float4*)(p1 + s * 32 + 4);
    } else {
      int k = (KSTEPS - 1) * 32 + lk * 8;
      if (k + 8 <= NF) {
        a0l = *(const float4*)(p0 + s * 32);
        a0h = *(const float4*)(p0 + s * 32 + 4);
        a1l = *(const float4*)(p1 + s * 32);
        a1h = *(const float4*)(p1 + s * 32 + 4);
      } else if (k + 4 <= NF) {
        a0l = *(const float4*)(p0 + s * 32); a0h = z4;
        a1l = *(const float4*)(p1 + s * 32); a1h = z4;
      } else {
        a0l = a0h = a1l = a1h = z4;
      }
    }
    short8v b[4];
#pragma unroll
    for (int f = 0; f < 4; ++f) b[f] = wfv[(s * 4 + f) * 64 + l];
    short8v a0, a1;
    a0[0] = f2bf(a0l.x); a0[1] = f2bf(a0l.y); a0[2] = f2bf(a0l.z); a0[3] = f2bf(a0l.w);
    a0[4] = f2bf(a0h.x); a0[5] = f2bf(a0h.y); a0[6] = f2bf(a0h.z); a0[7] = f2bf(a0h.w);
    a1[0] = f2bf(a1l.x); a1[1] = f2bf(a1l.y); a1[2] = f2bf(a1l.z); a1[3] = f2bf(a1l.w);
    a1[4] = f2bf(a1h.x); a1[5] = f2bf(a1h.y); a1[6] = f2bf(a1h.z); a1[7] = f2bf(a1h.w);
#pragma unroll
    for (int f = 0; f < 4; ++f) {
      acc[0][f] = __builtin_amdgcn_mfma_f32_16x16x32_bf16(a0, b[f], acc[0][f], 0, 0, 0);
      acc[1][f] = __builtin_amdgcn_mfma_f32_16x16x32_bf16(a1, b[f], acc[1][f], 0, 0, 0);
    }
  }

#pragma unroll
  for (int mi = 0; mi < 2; ++mi) {
    int nbase = n0 + mi * 16 + lk * 4;
#pragma unroll
    for (int f = 0; f < 4; ++f) {
      int ch = f * 16 + lr;
      float bb = b1[ch];
#pragma unroll
      for (int reg = 0; reg < 4; ++reg) {
        int nd = nbase + reg;
        if (nd < N) h1[(size_t)nd * HID + ch] = acc[mi][f][reg] + bb;
      }
    }
  }
}

// denominators; g1b = bf16(h1/D1); invD2 stored f32
__global__ void dpass_kernel(const int* __restrict__ off_src, const float* __restrict__ t_src,
                             const float* __restrict__ c, const float* __restrict__ h1,
                             unsigned short* __restrict__ g1b,
                             float* __restrict__ invD2, int N) {
  int node = blockIdx.x * 4 + (threadIdx.x >> 6);
  if (node >= N) return;
  int lane = threadIdx.x & 63;
  float c1p = c[lane], c1n = c[64 + lane];
  float c2p = lane < NCLS ? c[128 + lane] : 0.f;
  float c2n = lane < NCLS ? c[168 + lane] : 0.f;
  int b = off_src[node], e = off_src[node + 1];
  float d1 = 0.f, d2 = 0.f;
  for (int i = b; i < e; ++i) {
    float t = t_src[i];
    float s1 = t >= 0.f ? c1p : c1n;
    float s2 = t >= 0.f ? c2p : c2n;
    d1 += __expf(t * s1);
    d2 += __expf(t * s2);
  }
  float h = h1[(size_t)node * HID + lane];
  g1b[(size_t)node * HID + lane] = (unsigned short)f2bf(d1 > 0.f ? h / d1 : 0.f);
  if (lane < NCLS) invD2[(size_t)node * NCLS + lane] = d2 > 0.f ? 1.f / d2 : 0.f;
}

// out1[d,:] = sum_e exp(t*c1) * g1[src,:]; a1 = elu(out1)
__global__ void aggB_kernel(const int* __restrict__ off_dst, const long long* __restrict__ pair,
                            const float* __restrict__ c,
                            const unsigned short* __restrict__ g1b, float* __restrict__ a1, int N) {
  int node = blockIdx.x * 4 + (threadIdx.x >> 6);
  if (node >= N) return;
  int lane = threadIdx.x & 63;
  float c1p = c[lane], c1n = c[64 + lane];
  int b = off_dst[node], e = off_dst[node + 1];
  float acc = 0.f;
  int i = b;
  for (; i + 1 < e; i += 2) {
    long long p0 = __builtin_nontemporal_load(pair + i);
    long long p1 = __builtin_nontemporal_load(pair + i + 1);
    int s0 = (int)(unsigned)(p0 & 0xffffffffLL);
    int s1 = (int)(unsigned)(p1 & 0xffffffffLL);
    float t0 = __uint_as_float((unsigned)((unsigned long long)p0 >> 32));
    float t1 = __uint_as_float((unsigned)((unsigned long long)p1 >> 32));
    float ga = bf2f(g1b[(size_t)s0 * HID + lane]);
    float gb = bf2f(g1b[(size_t)s1 * HID + lane]);
    acc = fmaf(__expf(t0 * (t0 >= 0.f ? c1p : c1n)), ga, acc);
    acc = fmaf(__expf(t1 * (t1 >= 0.f ? c1p : c1n)), gb, acc);
  }
  if (i < e) {
    long long p0 = pair[i];
    int s0 = (int)(unsigned)(p0 & 0xffffffffLL);
    float t0 = __uint_as_float((unsigned)((unsigned long long)p0 >> 32));
    acc = fmaf(__expf(t0 * (t0 >= 0.f ? c1p : c1n)), bf2f(g1b[(size_t)s0 * HID + lane]), acc);
  }
  a1[(size_t)node * HID + lane] = acc > 0.f ? acc : __expf(acc) - 1.f;  // elu
}

// g2b = bf16((a1 @ w2 + b2) * invD2)   [N,40]
__global__ __launch_bounds__(256) void gemm2_kernel(const float* __restrict__ a1,
    const float* __restrict__ w2, const float* __restrict__ b2,
    const float* __restrict__ invD2, unsigned short* __restrict__ g2b, int N) {
  __shared__ float sa[32][65];
  __shared__ float sw[HID * NCLS];
  __shared__ float sb[NCLS];
  const int tid = threadIdx.x;
  const int n0 = blockIdx.x * 32;
  for (int i = tid; i < HID * NCLS; i += 256) sw[i] = w2[i];
  if (tid < NCLS) sb[tid] = b2[tid];
  for (int i = tid; i < 32 * HID; i += 256) {
    int r = i >> 6, col = i & 63;
    int node = n0 + r;
    sa[r][col] = node < N ? a1[(size_t)node * HID + col] : 0.f;
  }
  __syncthreads();
  const int r = tid >> 3;
  const int cg = (tid & 7) * 5;
  const int node = n0 + r;
  if (node >= N) return;
  float acc[5] = {};
  for (int k = 0; k < HID; ++k) {
    float a = sa[r][k];
#pragma unroll
    for (int u = 0; u < 5; ++u) acc[u] = fmaf(a, sw[k * NCLS + cg + u], acc[u]);
  }
#pragma unroll
  for (int u = 0; u < 5; ++u) {
    int ch = cg + u;
    g2b[(size_t)node * NCLS + ch] =
        (unsigned short)f2bf((acc[u] + sb[ch]) * invD2[(size_t)node * NCLS + ch]);
  }
}

// out2 + log_softmax
__global__ void aggC_kernel(const int* __restrict__ off_dst, const long long* __restrict__ pair,
                            const float* __restrict__ c,
                            const unsigned short* __restrict__ g2b, float* __restrict__ out, int N) {
  int node = blockIdx.x * 4 + (threadIdx.x >> 6);
  if (node >= N) return;
  int lane = threadIdx.x & 63;
  bool act = lane < NCLS;
  float c2p = act ? c[128 + lane] : 0.f;
  float c2n = act ? c[168 + lane] : 0.f;
  int b = off_dst[node], e = off_dst[node + 1];
  float acc = 0.f;
  int i = b;
  for (; i + 1 < e; i += 2) {
    long long p0 = __builtin_nontemporal_load(pair + i);
    long long p1 = __builtin_nontemporal_load(pair + i + 1);
    int s0 = (int)(unsigned)(p0 & 0xffffffffLL);
    int s1 = (int)(unsigned)(p1 & 0xffffffffLL);
    float t0 = __uint_as_float((unsigned)((unsigned long long)p0 >> 32));
    float t1 = __uint_as_float((unsigned)((unsigned long long)p1 >> 32));
    float ga = act ? bf2f(g2b[(size_t)s0 * NCLS + lane]) : 0.f;
    float gb = act ? bf2f(g2b[(size_t)s1 * NCLS + lane]) : 0.f;
    acc = fmaf(__expf(t0 * (t0 >= 0.f ? c2p : c2n)), ga, acc);
    acc = fmaf(__expf(t1 * (t1 >= 0.f ? c2p : c2n)), gb, acc);
  }
  if (i < e) {
    long long p0 = pair[i];
    int s0 = (int)(unsigned)(p0 & 0xffffffffLL);
    float t0 = __uint_as_float((unsigned)((unsigned long long)p0 >> 32));
    float ga = act ? bf2f(g2b[(size_t)s0 * NCLS + lane]) : 0.f;
    acc = fmaf(__expf(t0 * (t0 >= 0.f ? c2p : c2n)), ga, acc);
  }
  float v = act ? acc : -INFINITY;
  float m = v;
#pragma unroll
  for (int off = 32; off > 0; off >>= 1) m = fmaxf(m, __shfl_xor(m, off));
  float ex = act ? __expf(v - m) : 0.f;
  float s = ex;
#pragma unroll
  for (int off = 32; off > 0; off >>= 1) s += __shfl_xor(s, off);
  if (act) out[(size_t)node * NCLS + lane] = v - m - __logf(s);
}

extern "C" void kernel_launch(void* const* d_in, const int* in_sizes, int n_in,
                              void* d_out, int out_size, void* d_ws, size_t ws_size,
                              hipStream_t stream) {
  const float* x    = (const float*)d_in[0];
  const int*   ei   = (const int*)d_in[1];
  const float* wmul = (const float*)d_in[2];
  const float* w1   = (const float*)d_in[3];
  const float* b1   = (const float*)d_in[4];
  const float* m1a  = (const float*)d_in[5];
  const float* m1bw = (const float*)d_in[6];
  const float* w2   = (const float*)d_in[8];
  const float* b2   = (const float*)d_in[9];
  const float* m2a  = (const float*)d_in[10];
  const float* m2bw = (const float*)d_in[11];
  float* out = (float*)d_out;

  const int N = in_sizes[0] / NF;    // 100000
  const int E = in_sizes[2];         // 1600000

  char* ws = (char*)d_ws;
  size_t off = 0;
  auto carve = [&](size_t bytes) -> void* {
    void* p = ws + off;
    off = (off + bytes + 255) & ~(size_t)255;
    return p;
  };
  int*   off_src = (int*)carve((size_t)2 * (N + 1) * sizeof(int));
  int*   off_dst = off_src + (N + 1);
  int*   cur_src = (int*)carve((size_t)2 * N * sizeof(int));
  int*   cur_dst = cur_src + N;
  float* cvec    = (float*)carve(208 * sizeof(float));
  int*   psum    = (int*)carve(256 * sizeof(int));
  short* wf      = (short*)carve((size_t)KSTEPS * 4 * 64 * 8 * sizeof(short));
  float* t_src   = (float*)carve((size_t)E * sizeof(float));
  long long* pair = (long long*)carve((size_t)E * sizeof(long long));
  float* h1      = (float*)carve((size_t)N * HID * sizeof(float));
  float* invD2   = (float*)carve((size_t)N * NCLS * sizeof(float));
  float* a1      = (float*)carve((size_t)N * HID * sizeof(float));
  unsigned short* g1b = (unsigned short*)carve((size_t)N * HID * sizeof(unsigned short));
  unsigned short* g2b = (unsigned short*)h1;  // h1 (f32) dead after dpass; reuse for g2 bf16

  const int nc  = (N + SCHUNK - 1) / SCHUNK;
  const int rng = (N + NPART - 1) / NPART;

  hipMemsetAsync(off_src, 0, (size_t)2 * (N + 1) * sizeof(int), stream);
  prep_kernel<<<1, 64, 0, stream>>>(m1a, m1bw, m2a, m2bw, cvec);
  wprep_kernel<<<16, 256, 0, stream>>>(w1, wf);
  hist_kernel<<<(E + 255) / 256, 256, 0, stream>>>(ei, E, off_src, off_dst);
  scanA_kernel<<<2 * nc, 256, 0, stream>>>(off_src, off_dst, N, nc, psum);
  scanB_kernel<<<1, 64, 0, stream>>>(psum, nc, off_src, off_dst, N);
  scanC_kernel<<<2 * nc, 256, 0, stream>>>(off_src, cur_src, off_dst, cur_dst, N, nc, psum);
  scatter_kernel<<<NPART * ((E + 255) / 256), 256, 0, stream>>>(ei, wmul, E, cur_src, cur_dst,
                                                                t_src, pair, N, rng);
  gemm1_mfma<<<(N + 127) / 128, 256, 0, stream>>>(x, wf, b1, h1, N);
  dpass_kernel<<<(N + 3) / 4, 256, 0, stream>>>(off_src, t_src, cvec, h1, g1b, invD2, N);
  aggB_kernel<<<(N + 3) / 4, 256, 0, stream>>>(off_dst, pair, cvec, g1b, a1, N);
  gemm2_kernel<<<(N + 31) / 32, 256, 0, stream>>>(a1, w2, b2, invD2, g2b, N);
  aggC_kernel<<<(N + 3) / 4, 256, 0, stream>>>(off_dst, pair, cvec, g2b, out, N);
}

// Round 6
// 656.285 us; speedup vs baseline: 1.1242x; 1.1242x over previous
//
#include <hip/hip_runtime.h>
#include <hip/hip_bf16.h>
#include <math.h>

#define NF 500
#define HID 64
#define NCLS 40
#define NPART 8
#define SCHUNK 4096
#define KSTEPS 16   // ceil(500/32)

typedef __attribute__((ext_vector_type(8))) short short8v;
typedef __attribute__((ext_vector_type(4))) float f32x4v;

__device__ inline short f2bf(float f) {
  unsigned u = __float_as_uint(f);
  unsigned r = u + 0x7fff + ((u >> 16) & 1);   // RNE
  return (short)(r >> 16);
}
__device__ inline float bf2f(unsigned short u) {
  return __uint_as_float(((unsigned)u) << 16);
}

// cvec layout: [0,64) c1 slope for t>=0 ; [64,128) c1 slope for t<0 ;
//              [128,168) c2 slope for t>=0 ; [168,208) c2 slope for t<0

__global__ void prep_kernel(const float* __restrict__ m1a, const float* __restrict__ m1bw,
                            const float* __restrict__ m2a, const float* __restrict__ m2bw,
                            float* __restrict__ c) {
  int j = threadIdx.x;
  if (j < HID) {
    float sp = 0.f, sn = 0.f;
    for (int k = 0; k < HID; ++k) {
      float a = m1a[k];
      float ap = a > 0.f ? a : 0.2f * a;
      float an = a > 0.f ? 0.2f * a : a;
      float w = m1bw[k * HID + j];
      sp = fmaf(ap, w, sp);
      sn = fmaf(an, w, sn);
    }
    c[j] = sp;
    c[HID + j] = sn;
  }
  if (j < NCLS) {
    float sp = 0.f, sn = 0.f;
    for (int k = 0; k < NCLS; ++k) {
      float a = m2a[k];
      float ap = a > 0.f ? a : 0.2f * a;
      float an = a > 0.f ? 0.2f * a : a;
      float w = m2bw[k * NCLS + j];
      sp = fmaf(ap, w, sp);
      sn = fmaf(an, w, sn);
    }
    c[128 + j] = sp;
    c[168 + j] = sn;
  }
}

// w1 -> bf16 in B-fragment-linear layout
__global__ void wprep_kernel(const float* __restrict__ w1, short* __restrict__ wf) {
  int idx = blockIdx.x * 256 + threadIdx.x;   // 0..4095
  if (idx >= KSTEPS * 4 * 64) return;
  int l = idx & 63;
  int f = (idx >> 6) & 3;
  int s = idx >> 8;
  int ch = f * 16 + (l & 15);
  int kb = s * 32 + (l >> 4) * 8;
  short8v v;
#pragma unroll
  for (int j = 0; j < 8; ++j) {
    int k = kb + j;
    v[j] = (k < NF) ? f2bf(w1[(size_t)k * HID + ch]) : (short)0;
  }
  ((short8v*)wf)[idx] = v;
}

__global__ void hist_kernel(const int* __restrict__ ei, int E,
                            int* __restrict__ deg_src, int* __restrict__ deg_dst) {
  int i = blockIdx.x * blockDim.x + threadIdx.x;
  if (i < E) {
    int s = __builtin_nontemporal_load(ei + i);
    int d = __builtin_nontemporal_load(ei + E + i);
    atomicAdd(&deg_src[s], 1);
    atomicAdd(&deg_dst[d], 1);
  }
}

// ---- multi-block exclusive scan of two degree arrays ----
__global__ __launch_bounds__(256) void scanA_kernel(const int* __restrict__ a,
    const int* __restrict__ b, int n, int nc, int* __restrict__ part) {
  const int bi = blockIdx.x;
  const int* arr = (bi < nc) ? a : b;
  const int ci = (bi < nc) ? bi : bi - nc;
  const int base = ci * SCHUNK;
  int s = 0;
  for (int u = threadIdx.x; u < SCHUNK; u += 256) {
    int i = base + u;
    if (i < n) s += arr[i];
  }
  __shared__ int ws[4];
#pragma unroll
  for (int off = 32; off > 0; off >>= 1) s += __shfl_down(s, off);
  if ((threadIdx.x & 63) == 0) ws[threadIdx.x >> 6] = s;
  __syncthreads();
  if (threadIdx.x == 0) part[bi] = ws[0] + ws[1] + ws[2] + ws[3];
}

__global__ void scanB_kernel(int* __restrict__ part, int nc,
                             int* __restrict__ a, int* __restrict__ b, int n) {
  int lane = threadIdx.x;  // 64 threads
  for (int seg = 0; seg < 2; ++seg) {
    int v = (lane < nc) ? part[seg * nc + lane] : 0;
    int x = v;
#pragma unroll
    for (int off = 1; off < 64; off <<= 1) {
      int y = __shfl_up(x, off);
      if (lane >= off) x += y;
    }
    if (lane < nc) part[seg * nc + lane] = x - v;
    int tot = __shfl(x, 63);
    if (lane == 0) { if (seg == 0) a[n] = tot; else b[n] = tot; }
  }
}

__global__ __launch_bounds__(256) void scanC_kernel(int* __restrict__ a, int* __restrict__ cura,
    int* __restrict__ b, int* __restrict__ curb, int n, int nc, const int* __restrict__ part) {
  const int bi = blockIdx.x;
  int* arr; int* cur; int ci;
  if (bi < nc) { arr = a; cur = cura; ci = bi; }
  else         { arr = b; cur = curb; ci = bi - nc; }
  const int chunkoff = part[bi];
  const int base = ci * SCHUNK + threadIdx.x * 16;
  int v[16];
#pragma unroll
  for (int u = 0; u < 16; ++u) {
    int i = base + u;
    v[u] = (i < n) ? arr[i] : 0;
  }
  int tsum = 0;
#pragma unroll
  for (int u = 0; u < 16; ++u) tsum += v[u];
  const int lane = threadIdx.x & 63, wv = threadIdx.x >> 6;
  int x = tsum;
#pragma unroll
  for (int off = 1; off < 64; off <<= 1) {
    int y = __shfl_up(x, off);
    if (lane >= off) x += y;
  }
  __shared__ int ws[4];
  if (lane == 63) ws[wv] = x;
  __syncthreads();
  int woff = 0;
  for (int k = 0; k < wv; ++k) woff += ws[k];
  int toff = chunkoff + woff + x - tsum;
#pragma unroll
  for (int u = 0; u < 16; ++u) {
    int i = base + u;
    if (i < n) { arr[i] = toff; cur[i] = toff; }
    toff += v[u];
  }
}

// ---- partition-localized CSR scatter, nt streaming reads ----
// pair[] entries packed as (long long): low 32 = src index, high 32 = t bits
__global__ __launch_bounds__(256) void scatter_kernel(const int* __restrict__ ei,
    const float* __restrict__ wmul, int E,
    int* __restrict__ cur_src, int* __restrict__ cur_dst,
    float* __restrict__ t_src, long long* __restrict__ pair, int N, int rng) {
  const int part = blockIdx.x & (NPART - 1);
  const int e = (blockIdx.x >> 3) * 256 + threadIdx.x;
  if (e >= E) return;
  const int lo = part * rng;
  const int hi = min(N, lo + rng);
  int s = __builtin_nontemporal_load(ei + e);
  int d = __builtin_nontemporal_load(ei + E + e);
  bool ss = (s >= lo) && (s < hi);
  bool dd = (d >= lo) && (d < hi);
  if (!(ss || dd)) return;
  float t = __builtin_nontemporal_load(wmul + e);
  if (ss) { int ps = atomicAdd(&cur_src[s], 1); t_src[ps] = t; }
  if (dd) {
    int pd = atomicAdd(&cur_dst[d], 1);
    long long pk = (long long)((unsigned long long)(unsigned)__float_as_uint(t) << 32) |
                   (unsigned long long)(unsigned)s;
    pair[pd] = pk;
  }
}

// h1 = x @ w1 + b1 via bf16 MFMA
__global__ __launch_bounds__(256, 4) void gemm1_mfma(const float* __restrict__ x,
    const short* __restrict__ wf, const float* __restrict__ b1,
    float* __restrict__ h1, int N) {
  const int tid = threadIdx.x;
  const int wv = tid >> 6, l = tid & 63;
  const int lr = l & 15, lk = l >> 4;
  const int n0 = blockIdx.x * 128 + wv * 32;
  int r0 = n0 + lr, r1 = r0 + 16;
  const float* p0 = x + (size_t)min(r0, N - 1) * NF + lk * 8;
  const float* p1 = x + (size_t)min(r1, N - 1) * NF + lk * 8;
  const short8v* wfv = (const short8v*)wf;

  f32x4v acc[2][4];
#pragma unroll
  for (int mi = 0; mi < 2; ++mi)
#pragma unroll
    for (int f = 0; f < 4; ++f) acc[mi][f] = (f32x4v){0.f, 0.f, 0.f, 0.f};

  const float4 z4 = make_float4(0.f, 0.f, 0.f, 0.f);
#pragma unroll
  for (int s = 0; s < KSTEPS; ++s) {
    float4 a0l, a0h, a1l, a1h;
    if (s < KSTEPS - 1) {
      a0l = *(const float4*)(p0 + s * 32);
      a0h = *(const float4*)(p0 + s * 32 + 4);
      a1l = *(const float4*)(p1 + s * 32);
      a1h = *(const float4*)(p1 + s * 32 + 4);
    } else {
      int k = (KSTEPS - 1) * 32 + lk * 8;
      if (k + 8 <= NF) {
        a0l = *(const float4*)(p0 + s * 32);
        a0h = *(const float4*)(p0 + s * 32 + 4);
        a1l = *(const float4*)(p1 + s * 32);
        a1h = *(const float4*)(p1 + s * 32 + 4);
      } else if (k + 4 <= NF) {
        a0l = *(const float4*)(p0 + s * 32); a0h = z4;
        a1l = *(const float4*)(p1 + s * 32); a1h = z4;
      } else {
        a0l = a0h = a1l = a1h = z4;
      }
    }
    short8v b[4];
#pragma unroll
    for (int f = 0; f < 4; ++f) b[f] = wfv[(s * 4 + f) * 64 + l];
    short8v a0, a1;
    a0[0] = f2bf(a0l.x); a0[1] = f2bf(a0l.y); a0[2] = f2bf(a0l.z); a0[3] = f2bf(a0l.w);
    a0[4] = f2bf(a0h.x); a0[5] = f2bf(a0h.y); a0[6] = f2bf(a0h.z); a0[7] = f2bf(a0h.w);
    a1[0] = f2bf(a1l.x); a1[1] = f2bf(a1l.y); a1[2] = f2bf(a1l.z); a1[3] = f2bf(a1l.w);
    a1[4] = f2bf(a1h.x); a1[5] = f2bf(a1h.y); a1[6] = f2bf(a1h.z); a1[7] = f2bf(a1h.w);
#pragma unroll
    for (int f = 0; f < 4; ++f) {
      acc[0][f] = __builtin_amdgcn_mfma_f32_16x16x32_bf16(a0, b[f], acc[0][f], 0, 0, 0);
      acc[1][f] = __builtin_amdgcn_mfma_f32_16x16x32_bf16(a1, b[f], acc[1][f], 0, 0, 0);
    }
  }

#pragma unroll
  for (int mi = 0; mi < 2; ++mi) {
    int nbase = n0 + mi * 16 + lk * 4;
#pragma unroll
    for (int f = 0; f < 4; ++f) {
      int ch = f * 16 + lr;
      float bb = b1[ch];
#pragma unroll
      for (int reg = 0; reg < 4; ++reg) {
        int nd = nbase + reg;
        if (nd < N) h1[(size_t)nd * HID + ch] = acc[mi][f][reg] + bb;
      }
    }
  }
}

// denominators; g1b = bf16(h1/D1); invD2 stored f32
__global__ void dpass_kernel(const int* __restrict__ off_src, const float* __restrict__ t_src,
                             const float* __restrict__ c, const float* __restrict__ h1,
                             unsigned short* __restrict__ g1b,
                             float* __restrict__ invD2, int N) {
  int node = blockIdx.x * 4 + (threadIdx.x >> 6);
  if (node >= N) return;
  int lane = threadIdx.x & 63;
  float c1p = c[lane], c1n = c[64 + lane];
  float c2p = lane < NCLS ? c[128 + lane] : 0.f;
  float c2n = lane < NCLS ? c[168 + lane] : 0.f;
  int b = off_src[node], e = off_src[node + 1];
  float d1 = 0.f, d2 = 0.f;
  for (int i = b; i < e; ++i) {
    float t = t_src[i];
    float s1 = t >= 0.f ? c1p : c1n;
    float s2 = t >= 0.f ? c2p : c2n;
    d1 += __expf(t * s1);
    d2 += __expf(t * s2);
  }
  float h = h1[(size_t)node * HID + lane];
  g1b[(size_t)node * HID + lane] = (unsigned short)f2bf(d1 > 0.f ? h / d1 : 0.f);
  if (lane < NCLS) invD2[(size_t)node * NCLS + lane] = d2 > 0.f ? 1.f / d2 : 0.f;
}

// out1[d,:] = sum_e exp(t*c1) * g1[src,:]; a1 = elu(out1)
// 8-deep batched gathers for memory-level parallelism
__global__ void aggB_kernel(const int* __restrict__ off_dst, const long long* __restrict__ pair,
                            const float* __restrict__ c,
                            const unsigned short* __restrict__ g1b, float* __restrict__ a1, int N) {
  int node = blockIdx.x * 4 + (threadIdx.x >> 6);
  if (node >= N) return;
  int lane = threadIdx.x & 63;
  float c1p = c[lane], c1n = c[64 + lane];
  int b = off_dst[node], e = off_dst[node + 1];
  float acc = 0.f;
  int i = b;
  for (; i + 8 <= e; i += 8) {
    long long p[8];
#pragma unroll
    for (int u = 0; u < 8; ++u) p[u] = pair[i + u];
    float gv[8];
#pragma unroll
    for (int u = 0; u < 8; ++u) {
      int s = (int)(unsigned)(p[u] & 0xffffffffLL);
      gv[u] = bf2f(g1b[(size_t)s * HID + lane]);
    }
#pragma unroll
    for (int u = 0; u < 8; ++u) {
      float t = __uint_as_float((unsigned)((unsigned long long)p[u] >> 32));
      acc = fmaf(__expf(t * (t >= 0.f ? c1p : c1n)), gv[u], acc);
    }
  }
  for (; i < e; ++i) {
    long long p0 = pair[i];
    int s0 = (int)(unsigned)(p0 & 0xffffffffLL);
    float t0 = __uint_as_float((unsigned)((unsigned long long)p0 >> 32));
    acc = fmaf(__expf(t0 * (t0 >= 0.f ? c1p : c1n)), bf2f(g1b[(size_t)s0 * HID + lane]), acc);
  }
  a1[(size_t)node * HID + lane] = acc > 0.f ? acc : __expf(acc) - 1.f;  // elu
}

// g2b = bf16((a1 @ w2 + b2) * invD2)   [N,40]
__global__ __launch_bounds__(256) void gemm2_kernel(const float* __restrict__ a1,
    const float* __restrict__ w2, const float* __restrict__ b2,
    const float* __restrict__ invD2, unsigned short* __restrict__ g2b, int N) {
  __shared__ float sa[32][65];
  __shared__ float sw[HID * NCLS];
  __shared__ float sb[NCLS];
  const int tid = threadIdx.x;
  const int n0 = blockIdx.x * 32;
  for (int i = tid; i < HID * NCLS; i += 256) sw[i] = w2[i];
  if (tid < NCLS) sb[tid] = b2[tid];
  for (int i = tid; i < 32 * HID; i += 256) {
    int r = i >> 6, col = i & 63;
    int node = n0 + r;
    sa[r][col] = node < N ? a1[(size_t)node * HID + col] : 0.f;
  }
  __syncthreads();
  const int r = tid >> 3;
  const int cg = (tid & 7) * 5;
  const int node = n0 + r;
  if (node >= N) return;
  float acc[5] = {};
  for (int k = 0; k < HID; ++k) {
    float a = sa[r][k];
#pragma unroll
    for (int u = 0; u < 5; ++u) acc[u] = fmaf(a, sw[k * NCLS + cg + u], acc[u]);
  }
#pragma unroll
  for (int u = 0; u < 5; ++u) {
    int ch = cg + u;
    g2b[(size_t)node * NCLS + ch] =
        (unsigned short)f2bf((acc[u] + sb[ch]) * invD2[(size_t)node * NCLS + ch]);
  }
}

// out2 + log_softmax, 8-deep batched gathers
__global__ void aggC_kernel(const int* __restrict__ off_dst, const long long* __restrict__ pair,
                            const float* __restrict__ c,
                            const unsigned short* __restrict__ g2b, float* __restrict__ out, int N) {
  int node = blockIdx.x * 4 + (threadIdx.x >> 6);
  if (node >= N) return;
  int lane = threadIdx.x & 63;
  bool act = lane < NCLS;
  float c2p = act ? c[128 + lane] : 0.f;
  float c2n = act ? c[168 + lane] : 0.f;
  int b = off_dst[node], e = off_dst[node + 1];
  float acc = 0.f;
  int i = b;
  for (; i + 8 <= e; i += 8) {
    long long p[8];
#pragma unroll
    for (int u = 0; u < 8; ++u) p[u] = pair[i + u];
    float gv[8];
#pragma unroll
    for (int u = 0; u < 8; ++u) {
      int s = (int)(unsigned)(p[u] & 0xffffffffLL);
      gv[u] = act ? bf2f(g2b[(size_t)s * NCLS + lane]) : 0.f;
    }
#pragma unroll
    for (int u = 0; u < 8; ++u) {
      float t = __uint_as_float((unsigned)((unsigned long long)p[u] >> 32));
      acc = fmaf(__expf(t * (t >= 0.f ? c2p : c2n)), gv[u], acc);
    }
  }
  for (; i < e; ++i) {
    long long p0 = pair[i];
    int s0 = (int)(unsigned)(p0 & 0xffffffffLL);
    float t0 = __uint_as_float((unsigned)((unsigned long long)p0 >> 32));
    float ga = act ? bf2f(g2b[(size_t)s0 * NCLS + lane]) : 0.f;
    acc = fmaf(__expf(t0 * (t0 >= 0.f ? c2p : c2n)), ga, acc);
  }
  float v = act ? acc : -INFINITY;
  float m = v;
#pragma unroll
  for (int off = 32; off > 0; off >>= 1) m = fmaxf(m, __shfl_xor(m, off));
  float ex = act ? __expf(v - m) : 0.f;
  float s = ex;
#pragma unroll
  for (int off = 32; off > 0; off >>= 1) s += __shfl_xor(s, off);
  if (act) out[(size_t)node * NCLS + lane] = v - m - __logf(s);
}

extern "C" void kernel_launch(void* const* d_in, const int* in_sizes, int n_in,
                              void* d_out, int out_size, void* d_ws, size_t ws_size,
                              hipStream_t stream) {
  const float* x    = (const float*)d_in[0];
  const int*   ei   = (const int*)d_in[1];
  const float* wmul = (const float*)d_in[2];
  const float* w1   = (const float*)d_in[3];
  const float* b1   = (const float*)d_in[4];
  const float* m1a  = (const float*)d_in[5];
  const float* m1bw = (const float*)d_in[6];
  const float* w2   = (const float*)d_in[8];
  const float* b2   = (const float*)d_in[9];
  const float* m2a  = (const float*)d_in[10];
  const float* m2bw = (const float*)d_in[11];
  float* out = (float*)d_out;

  const int N = in_sizes[0] / NF;    // 100000
  const int E = in_sizes[2];         // 1600000

  char* ws = (char*)d_ws;
  size_t off = 0;
  auto carve = [&](size_t bytes) -> void* {
    void* p = ws + off;
    off = (off + bytes + 255) & ~(size_t)255;
    return p;
  };
  int*   off_src = (int*)carve((size_t)2 * (N + 1) * sizeof(int));
  int*   off_dst = off_src + (N + 1);
  int*   cur_src = (int*)carve((size_t)2 * N * sizeof(int));
  int*   cur_dst = cur_src + N;
  float* cvec    = (float*)carve(208 * sizeof(float));
  int*   psum    = (int*)carve(256 * sizeof(int));
  short* wf      = (short*)carve((size_t)KSTEPS * 4 * 64 * 8 * sizeof(short));
  float* t_src   = (float*)carve((size_t)E * sizeof(float));
  long long* pair = (long long*)carve((size_t)E * sizeof(long long));
  float* h1      = (float*)carve((size_t)N * HID * sizeof(float));
  float* invD2   = (float*)carve((size_t)N * NCLS * sizeof(float));
  float* a1      = (float*)carve((size_t)N * HID * sizeof(float));
  unsigned short* g1b = (unsigned short*)carve((size_t)N * HID * sizeof(unsigned short));
  unsigned short* g2b = (unsigned short*)h1;  // h1 (f32) dead after dpass; reuse for g2 bf16

  const int nc  = (N + SCHUNK - 1) / SCHUNK;
  const int rng = (N + NPART - 1) / NPART;

  hipMemsetAsync(off_src, 0, (size_t)2 * (N + 1) * sizeof(int), stream);
  prep_kernel<<<1, 64, 0, stream>>>(m1a, m1bw, m2a, m2bw, cvec);
  wprep_kernel<<<16, 256, 0, stream>>>(w1, wf);
  hist_kernel<<<(E + 255) / 256, 256, 0, stream>>>(ei, E, off_src, off_dst);
  scanA_kernel<<<2 * nc, 256, 0, stream>>>(off_src, off_dst, N, nc, psum);
  scanB_kernel<<<1, 64, 0, stream>>>(psum, nc, off_src, off_dst, N);
  scanC_kernel<<<2 * nc, 256, 0, stream>>>(off_src, cur_src, off_dst, cur_dst, N, nc, psum);
  scatter_kernel<<<NPART * ((E + 255) / 256), 256, 0, stream>>>(ei, wmul, E, cur_src, cur_dst,
                                                                t_src, pair, N, rng);
  gemm1_mfma<<<(N + 127) / 128, 256, 0, stream>>>(x, wf, b1, h1, N);
  dpass_kernel<<<(N + 3) / 4, 256, 0, stream>>>(off_src, t_src, cvec, h1, g1b, invD2, N);
  aggB_kernel<<<(N + 3) / 4, 256, 0, stream>>>(off_dst, pair, cvec, g1b, a1, N);
  gemm2_kernel<<<(N + 31) / 32, 256, 0, stream>>>(a1, w2, b2, invD2, g2b, N);
  aggC_kernel<<<(N + 3) / 4, 256, 0, stream>>>(off_dst, pair, cvec, g2b, out, N);
}